// Round 1
// baseline (272.995 us; speedup 1.0000x reference)
//
#include <hip/hip_runtime.h>
#include <hip/hip_bf16.h>
#include <stdint.h>

typedef unsigned short u16;
typedef float f32x4 __attribute__((ext_vector_type(4)));
typedef short s16x8 __attribute__((ext_vector_type(8)));

#define N_EMBD 2048
#define HS 128
#define BATCH 4
#define SEQ 2048
#define M_TOT (BATCH * SEQ)   /* 8192 */

__device__ __forceinline__ u16 f2bf(float f) {
    unsigned int u = __float_as_uint(f);
    unsigned int r = u + 0x7FFFu + ((u >> 16) & 1u);   // round-to-nearest-even
    return (u16)(r >> 16);
}

// D = A(16x32) * B(32x16) + D, bf16 inputs, fp32 acc.
// A frag: lane holds A[lane&15][8*(lane>>4)+j]; B frag: B[8*(lane>>4)+j][lane&15]
// D: D[(lane>>4)*4 + r][lane&15]
__device__ __forceinline__ void mfma16(f32x4& d, s16x8 a, s16x8 b) {
    asm("v_mfma_f32_16x16x32_bf16 %0, %1, %2, %0" : "+v"(d) : "v"(a), "v"(b));
}

// ---------------- kernel 0: x fp32 -> bf16 ----------------
__global__ void cvt_x(const float* __restrict__ x, u16* __restrict__ xb) {
    long i = (long)blockIdx.x * blockDim.x + threadIdx.x;   // 0..2097151, 8 elems each
    const float4* x4 = (const float4*)x + i * 2;
    float4 a = x4[0], b = x4[1];
    s16x8 v;
    v[0] = (short)f2bf(a.x); v[1] = (short)f2bf(a.y);
    v[2] = (short)f2bf(a.z); v[3] = (short)f2bf(a.w);
    v[4] = (short)f2bf(b.x); v[5] = (short)f2bf(b.y);
    v[6] = (short)f2bf(b.z); v[7] = (short)f2bf(b.w);
    *(s16x8*)(xb + i * 8) = v;
}

// ---------------- kernel 1: W [2048][128] fp32 -> wT bf16 [mat][128][2048] ----------------
__global__ void cvt_w(const float* __restrict__ wq, const float* __restrict__ wk,
                      const float* __restrict__ wv, u16* __restrict__ wt) {
    int e = blockIdx.x * 256 + threadIdx.x;     // 0..262143
    int mat = blockIdx.y;
    const float* w = (mat == 0) ? wq : ((mat == 1) ? wk : wv);
    int k = e >> 7, n = e & 127;
    wt[(size_t)mat * (HS * N_EMBD) + (size_t)n * N_EMBD + k] = f2bf(w[e]);
}

// ---------------- kernel 2: projection GEMM ----------------
// out[m][n] = sum_k xb[m][k] * w[k][n]  (+bias, q scaled by 1/sqrt(2048))
// 128x128 tile, BK=64, 4 waves (2x2), per-wave 64x64 = 4x4 frags of 16x16
__launch_bounds__(256)
__global__ void proj(const u16* __restrict__ xb, const u16* __restrict__ wt,
                     const float* __restrict__ bq, const float* __restrict__ bk,
                     const float* __restrict__ bv,
                     u16* __restrict__ q_ws, u16* __restrict__ k_ws, u16* __restrict__ vt_ws) {
    __shared__ u16 as_[128 * 72];   // row stride 72 elems (144B): 2-way bank conflicts only
    __shared__ u16 bs_[128 * 72];
    int tid = threadIdx.x;
    int mat = blockIdx.y;
    int mbase = blockIdx.x * 128;
    const u16* wtm = wt + (size_t)mat * (HS * N_EMBD);
    int lane = tid & 63, w = tid >> 6;
    int wr = w >> 1, wc = w & 1;
    int g = lane >> 4, c = lane & 15;

    f32x4 acc[4][4] = {};

    for (int kt = 0; kt < N_EMBD / 64; ++kt) {
        int k0 = kt * 64;
#pragma unroll
        for (int i = 0; i < 4; ++i) {
            int chunk = i * 256 + tid;            // 1024 chunks of 8 bf16
            int row = chunk >> 3, cc = chunk & 7;
            s16x8 va = *(const s16x8*)(xb + (size_t)(mbase + row) * N_EMBD + k0 + cc * 8);
            *(s16x8*)(as_ + row * 72 + cc * 8) = va;
            s16x8 vb = *(const s16x8*)(wtm + (size_t)row * N_EMBD + k0 + cc * 8);
            *(s16x8*)(bs_ + row * 72 + cc * 8) = vb;
        }
        __syncthreads();
#pragma unroll
        for (int kk = 0; kk < 2; ++kk) {
            s16x8 af[4], bf[4];
#pragma unroll
            for (int mi = 0; mi < 4; ++mi)
                af[mi] = *(const s16x8*)(as_ + (wr * 64 + mi * 16 + c) * 72 + kk * 32 + 8 * g);
#pragma unroll
            for (int ni = 0; ni < 4; ++ni)
                bf[ni] = *(const s16x8*)(bs_ + (wc * 64 + ni * 16 + c) * 72 + kk * 32 + 8 * g);
#pragma unroll
            for (int mi = 0; mi < 4; ++mi)
#pragma unroll
                for (int ni = 0; ni < 4; ++ni)
                    mfma16(acc[mi][ni], af[mi], bf[ni]);
        }
        __syncthreads();
    }

    const float* bias = (mat == 0) ? bq : ((mat == 1) ? bk : bv);
    float scale = (mat == 0) ? 0.022097086912079608f : 1.0f;   // fold 1/sqrt(2048) into q
#pragma unroll
    for (int ni = 0; ni < 4; ++ni) {
        int col = wc * 64 + ni * 16 + c;
        float bsv = bias[col];
#pragma unroll
        for (int mi = 0; mi < 4; ++mi) {
#pragma unroll
            for (int r = 0; r < 4; ++r) {
                int gm = mbase + wr * 64 + mi * 16 + g * 4 + r;
                u16 hv = f2bf((acc[mi][ni][r] + bsv) * scale);
                if (mat == 0)      q_ws[(size_t)gm * HS + col] = hv;
                else if (mat == 1) k_ws[(size_t)gm * HS + col] = hv;
                else {
                    int b = gm >> 11, t = gm & 2047;
                    vt_ws[(size_t)b * HS * SEQ + (size_t)col * SEQ + t] = hv;  // V^T [b][d][t]
                }
            }
        }
    }
}

// ---------------- kernel 3: causal flash attention ----------------
// block: 128 threads (2 waves), each wave owns 16 q rows; QBLK=32, KVBLK=64
__launch_bounds__(128)
__global__ void attn(const u16* __restrict__ q_ws, const u16* __restrict__ k_ws,
                     const u16* __restrict__ vt_ws, float* __restrict__ out) {
    __shared__ u16 ks[64 * 128];      // [kv][d], 16B chunks XOR-swizzled by (row&7)
    __shared__ u16 vs[128 * 64];      // [d][kv], swizzled by (d&7)
    __shared__ u16 ps[2 * 16 * 72];   // per-wave P tile, padded stride 72
    int tid = threadIdx.x;
    int lane = tid & 63, w = tid >> 6;
    int g = lane >> 4, c = lane & 15;
    int qt = blockIdx.x, b = blockIdx.y;
    int q0 = qt * 32;
    int qrow = q0 + w * 16;
    const u16* qp = q_ws + (size_t)(b * SEQ) * HS;
    const u16* kp = k_ws + (size_t)(b * SEQ) * HS;
    const u16* vp = vt_ws + (size_t)b * HS * SEQ;

    s16x8 qf[4];
#pragma unroll
    for (int kk = 0; kk < 4; ++kk)
        qf[kk] = *(const s16x8*)(qp + (size_t)(qrow + c) * HS + kk * 32 + 8 * g);

    f32x4 o[8] = {};
    float m[4], l[4];
#pragma unroll
    for (int r = 0; r < 4; ++r) { m[r] = -1e30f; l[r] = 0.f; }

    int nt = (q0 + 32 + 63) >> 6;   // kv tiles; last tile start <= q0 always
    for (int t = 0; t < nt; ++t) {
        int kv0 = t * 64;
#pragma unroll
        for (int i = 0; i < 8; ++i) {
            int chunk = i * 128 + tid;
            int row = chunk >> 4, cc = chunk & 15;   // K: 64 rows x 16 chunks
            s16x8 va = *(const s16x8*)(kp + (size_t)(kv0 + row) * HS + cc * 8);
            *(s16x8*)(ks + row * 128 + ((cc ^ (row & 7)) * 8)) = va;
            int d = chunk >> 3, c2 = chunk & 7;      // V^T: 128 rows x 8 chunks
            s16x8 vb = *(const s16x8*)(vp + (size_t)d * SEQ + kv0 + c2 * 8);
            *(s16x8*)(vs + d * 64 + ((c2 ^ (d & 7)) * 8)) = vb;
        }
        __syncthreads();

        // S = Q K^T  (scale pre-folded into q)
        f32x4 s[4];
#pragma unroll
        for (int sub = 0; sub < 4; ++sub) {
            s[sub] = (f32x4){0.f, 0.f, 0.f, 0.f};
#pragma unroll
            for (int kk = 0; kk < 4; ++kk) {
                int row = sub * 16 + c;
                s16x8 kf = *(const s16x8*)(ks + row * 128 + (((kk * 4 + g) ^ (row & 7)) * 8));
                mfma16(s[sub], qf[kk], kf);
            }
        }
        // causal mask + per-row tile max
        float mt[4];
#pragma unroll
        for (int r = 0; r < 4; ++r) mt[r] = -1e30f;
#pragma unroll
        for (int sub = 0; sub < 4; ++sub) {
            int col = kv0 + sub * 16 + c;
#pragma unroll
            for (int r = 0; r < 4; ++r) {
                int rq = qrow + g * 4 + r;
                if (col > rq) s[sub][r] = -1e30f;
                mt[r] = fmaxf(mt[r], s[sub][r]);
            }
        }
#pragma unroll
        for (int r = 0; r < 4; ++r) {
            mt[r] = fmaxf(mt[r], __shfl_xor(mt[r], 1));
            mt[r] = fmaxf(mt[r], __shfl_xor(mt[r], 2));
            mt[r] = fmaxf(mt[r], __shfl_xor(mt[r], 4));
            mt[r] = fmaxf(mt[r], __shfl_xor(mt[r], 8));
        }
        float rs[4], sc[4];
#pragma unroll
        for (int r = 0; r < 4; ++r) {
            float mn = fmaxf(m[r], mt[r]);
            sc[r] = __expf(m[r] - mn);
            m[r] = mn;
            rs[r] = 0.f;
        }
#pragma unroll
        for (int sub = 0; sub < 4; ++sub)
#pragma unroll
            for (int r = 0; r < 4; ++r) {
                float p = __expf(s[sub][r] - m[r]);
                s[sub][r] = p;
                rs[r] += p;
            }
#pragma unroll
        for (int r = 0; r < 4; ++r) {
            rs[r] += __shfl_xor(rs[r], 1);
            rs[r] += __shfl_xor(rs[r], 2);
            rs[r] += __shfl_xor(rs[r], 4);
            rs[r] += __shfl_xor(rs[r], 8);
            l[r] = l[r] * sc[r] + rs[r];
        }
#pragma unroll
        for (int n = 0; n < 8; ++n)
#pragma unroll
            for (int r = 0; r < 4; ++r) o[n][r] *= sc[r];

        // P (D-layout) -> LDS -> A-layout frags (wave-private buffer, no barrier needed)
#pragma unroll
        for (int sub = 0; sub < 4; ++sub)
#pragma unroll
            for (int r = 0; r < 4; ++r)
                ps[w * 1152 + (g * 4 + r) * 72 + sub * 16 + c] = f2bf(s[sub][r]);

#pragma unroll
        for (int kk = 0; kk < 2; ++kk) {
            s16x8 pf = *(const s16x8*)(ps + w * 1152 + c * 72 + kk * 32 + 8 * g);
#pragma unroll
            for (int n = 0; n < 8; ++n) {
                int d = n * 16 + c;
                s16x8 vf = *(const s16x8*)(vs + d * 64 + (((kk * 4 + g) ^ (d & 7)) * 8));
                mfma16(o[n], pf, vf);
            }
        }
        __syncthreads();   // protect ks/vs before next tile's staging
    }

    float* op = out + (size_t)(b * SEQ + qrow) * HS;
#pragma unroll
    for (int r = 0; r < 4; ++r) {
        float inv = 1.0f / l[r];
#pragma unroll
        for (int n = 0; n < 8; ++n)
            op[(size_t)(g * 4 + r) * HS + n * 16 + c] = o[n][r] * inv;
    }
}

extern "C" void kernel_launch(void* const* d_in, const int* in_sizes, int n_in,
                              void* d_out, int out_size, void* d_ws, size_t ws_size,
                              hipStream_t stream) {
    const float* x  = (const float*)d_in[0];
    const float* wq = (const float*)d_in[1];
    const float* bq = (const float*)d_in[2];
    const float* wk = (const float*)d_in[3];
    const float* bk = (const float*)d_in[4];
    const float* wv = (const float*)d_in[5];
    const float* bv = (const float*)d_in[6];
    float* out = (float*)d_out;

    char* ws = (char*)d_ws;
    u16* xb    = (u16*)ws;                                   // 8192*2048*2  = 32 MB
    u16* wt    = (u16*)(ws + (size_t)33554432);              // 3*128*2048*2 = 1.5 MB
    u16* q_ws  = (u16*)(ws + (size_t)33554432 + 1572864);    // 2 MB
    u16* k_ws  = q_ws + (size_t)M_TOT * HS;                  // 2 MB
    u16* vt_ws = k_ws + (size_t)M_TOT * HS;                  // 2 MB

    hipLaunchKernelGGL(cvt_x, dim3(8192), dim3(256), 0, stream, x, xb);
    hipLaunchKernelGGL(cvt_w, dim3(1024, 3), dim3(256), 0, stream, wq, wk, wv, wt);
    hipLaunchKernelGGL(proj, dim3(64, 3), dim3(256), 0, stream,
                       xb, wt, bq, bk, bv, q_ws, k_ws, vt_ws);
    hipLaunchKernelGGL(attn, dim3(64, 4), dim3(128), 0, stream, q_ws, k_ws, vt_ws, out);
}

// Round 2
// 189.847 us; speedup vs baseline: 1.4380x; 1.4380x over previous
//
#include <hip/hip_runtime.h>
#include <hip/hip_bf16.h>
#include <stdint.h>

typedef unsigned short u16;
typedef float f32x4 __attribute__((ext_vector_type(4)));
typedef short s16x8 __attribute__((ext_vector_type(8)));

#define N_EMBD 2048
#define HS 128
#define BATCH 4
#define SEQ 2048
#define M_TOT (BATCH * SEQ)   /* 8192 */

__device__ __forceinline__ u16 f2bf(float f) {
    unsigned int u = __float_as_uint(f);
    unsigned int r = u + 0x7FFFu + ((u >> 16) & 1u);   // round-to-nearest-even
    return (u16)(r >> 16);
}
__device__ __forceinline__ float bf2f(u16 h) {
    return __uint_as_float(((unsigned int)h) << 16);
}

// D = A(16x32)*B(32x16) + D. A frag: lane holds A[lane&15][8*(lane>>4)+j];
// B frag: B[8*(lane>>4)+j][lane&15]; D: D[(lane>>4)*4+r][lane&15]
__device__ __forceinline__ void mfma16(f32x4& d, s16x8 a, s16x8 b) {
    asm("v_mfma_f32_16x16x32_bf16 %0, %1, %2, %0" : "+v"(d) : "v"(a), "v"(b));
}

// ---------------- W [2048][128] fp32 -> wT bf16 [mat][128][2048] ----------------
__global__ void cvt_w(const float* __restrict__ wq, const float* __restrict__ wk,
                      const float* __restrict__ wv, u16* __restrict__ wt) {
    int e = blockIdx.x * 256 + threadIdx.x;     // 0..262143
    int mat = blockIdx.y;
    const float* w = (mat == 0) ? wq : ((mat == 1) ? wk : wv);
    int k = e >> 7, n = e & 127;
    wt[(size_t)mat * (HS * N_EMBD) + (size_t)n * N_EMBD + k] = f2bf(w[e]);
}

// ---------------- projection GEMM, split-K=4, fused x fp32->bf16 ----------------
// grid (64 Mtiles, 3 mats, 4 ksplits). 128x128 tile, BK=64, 4 waves 2x2.
// writes bf16 partials part[kz][mat][8192][128] (no bias yet)
__launch_bounds__(256)
__global__ void proj_sk(const float* __restrict__ x, const u16* __restrict__ wt,
                        u16* __restrict__ part) {
    __shared__ u16 as_[128 * 72];   // stride 72 elems: 2-way conflicts only (free)
    __shared__ u16 bs_[128 * 72];
    int tid = threadIdx.x;
    int lane = tid & 63, w = tid >> 6;
    int wr = w >> 1, wc = w & 1;
    int g = lane >> 4, c = lane & 15;
    int mat = blockIdx.y, kz = blockIdx.z;
    int mbase = blockIdx.x * 128, kbase = kz * 512;
    const u16* wtm = wt + (size_t)mat * (HS * N_EMBD);

    f32x4 acc[4][4] = {};

    for (int kt = 0; kt < 8; ++kt) {
        int k0 = kbase + kt * 64;
#pragma unroll
        for (int i = 0; i < 4; ++i) {
            int chunk = i * 256 + tid;            // 1024 chunks of 8 elems
            int row = chunk >> 3, cc = chunk & 7;
            const float4* xp = (const float4*)(x + (size_t)(mbase + row) * N_EMBD + k0 + cc * 8);
            float4 a = xp[0], b = xp[1];
            s16x8 v;
            v[0] = (short)f2bf(a.x); v[1] = (short)f2bf(a.y);
            v[2] = (short)f2bf(a.z); v[3] = (short)f2bf(a.w);
            v[4] = (short)f2bf(b.x); v[5] = (short)f2bf(b.y);
            v[6] = (short)f2bf(b.z); v[7] = (short)f2bf(b.w);
            *(s16x8*)(as_ + row * 72 + cc * 8) = v;
            *(s16x8*)(bs_ + row * 72 + cc * 8) =
                *(const s16x8*)(wtm + (size_t)row * N_EMBD + k0 + cc * 8);
        }
        __syncthreads();
#pragma unroll
        for (int kk = 0; kk < 2; ++kk) {
            s16x8 af[4], bf[4];
#pragma unroll
            for (int mi = 0; mi < 4; ++mi)
                af[mi] = *(const s16x8*)(as_ + (wr * 64 + mi * 16 + c) * 72 + kk * 32 + 8 * g);
#pragma unroll
            for (int ni = 0; ni < 4; ++ni)
                bf[ni] = *(const s16x8*)(bs_ + (wc * 64 + ni * 16 + c) * 72 + kk * 32 + 8 * g);
#pragma unroll
            for (int mi = 0; mi < 4; ++mi)
#pragma unroll
                for (int ni = 0; ni < 4; ++ni)
                    mfma16(acc[mi][ni], af[mi], bf[ni]);
        }
        __syncthreads();
    }

    u16* pp = part + (size_t)(kz * 3 + mat) * M_TOT * HS;
#pragma unroll
    for (int ni = 0; ni < 4; ++ni) {
        int col = wc * 64 + ni * 16 + c;
#pragma unroll
        for (int mi = 0; mi < 4; ++mi)
#pragma unroll
            for (int r = 0; r < 4; ++r) {
                int gm = mbase + wr * 64 + mi * 16 + g * 4 + r;
                pp[(size_t)gm * HS + col] = f2bf(acc[mi][ni][r]);
            }
    }
}

// ---------------- reduce partials -> q_ws / k_ws (bf16, bias, q scale) ----------------
__global__ void reduce_qk(const u16* __restrict__ part, const float* __restrict__ bq,
                          const float* __restrict__ bk,
                          u16* __restrict__ q_ws, u16* __restrict__ k_ws) {
    int cid = blockIdx.x * 256 + threadIdx.x;   // 0..262143
    int mat = cid >> 17, rem = cid & 131071;
    int gm = rem >> 4, c8 = (rem & 15) * 8;
    float s[8] = {0.f, 0.f, 0.f, 0.f, 0.f, 0.f, 0.f, 0.f};
#pragma unroll
    for (int kz = 0; kz < 4; ++kz) {
        s16x8 v = *(const s16x8*)(part + ((size_t)(kz * 3 + mat) * M_TOT + gm) * HS + c8);
#pragma unroll
        for (int j = 0; j < 8; ++j) s[j] += bf2f((u16)v[j]);
    }
    const float* bias = mat ? bk : bq;
    float scale = mat ? 1.0f : 0.022097086912079608f;   // 1/sqrt(2048) folded into q
    s16x8 o;
#pragma unroll
    for (int j = 0; j < 8; ++j) o[j] = (short)f2bf((s[j] + bias[c8 + j]) * scale);
    u16* dst = mat ? k_ws : q_ws;
    *(s16x8*)(dst + (size_t)gm * HS + c8) = o;
}

// ---------------- reduce partials -> vT bf16 [b][d][t] (LDS transpose) ----------------
__global__ void reduce_v(const u16* __restrict__ part, const float* __restrict__ bv,
                         u16* __restrict__ vt_ws) {
    __shared__ float td[64][132];
    int tid = threadIdx.x;
    int tb = blockIdx.x, b = blockIdx.y;
#pragma unroll
    for (int i = 0; i < 4; ++i) {
        int chunk = i * 256 + tid;               // 1024 chunks: 64 rows x 16 col-chunks
        int row = chunk >> 4, c8 = (chunk & 15) * 8;
        int gm = b * SEQ + tb * 64 + row;
        float s[8] = {0.f, 0.f, 0.f, 0.f, 0.f, 0.f, 0.f, 0.f};
#pragma unroll
        for (int kz = 0; kz < 4; ++kz) {
            s16x8 v = *(const s16x8*)(part + ((size_t)(kz * 3 + 2) * M_TOT + gm) * HS + c8);
#pragma unroll
            for (int j = 0; j < 8; ++j) s[j] += bf2f((u16)v[j]);
        }
        *(float4*)&td[row][c8]     = (float4){s[0], s[1], s[2], s[3]};
        *(float4*)&td[row][c8 + 4] = (float4){s[4], s[5], s[6], s[7]};
    }
    __syncthreads();
    int d = tid >> 1, th = tid & 1;
    float bvd = bv[d];
#pragma unroll
    for (int jj = 0; jj < 4; ++jj) {
        s16x8 o;
#pragma unroll
        for (int e = 0; e < 8; ++e) {
            int t = th * 32 + jj * 8 + e;
            o[e] = (short)f2bf(td[t][d] + bvd);
        }
        *(s16x8*)(vt_ws + ((size_t)b * HS + d) * SEQ + tb * 64 + th * 32 + jj * 8) = o;
    }
}

// ---------------- causal flash attention, KV-split-4 partials ----------------
// grid 1024 = (qt 64) x (qz 4) x (b 4); block 128 thr (2 waves, 16 q rows each).
// Block handles tiles t = qz, qz+4, ... < nt. Writes unnormalized o + (m,l) f32.
__launch_bounds__(128)
__global__ void attn_part(const u16* __restrict__ q_ws, const u16* __restrict__ k_ws,
                          const u16* __restrict__ vt_ws,
                          float* __restrict__ pa_o, float* __restrict__ pa_m,
                          float* __restrict__ pa_l) {
    __shared__ u16 ks[64 * 128];      // [kv][d], 16B chunks XOR-swizzled by (row&7)
    __shared__ u16 vs[128 * 64];      // [d][kv], swizzled by (d&7)
    __shared__ u16 ps[2 * 16 * 72];   // per-wave P tile, padded stride 72
    int tid = threadIdx.x;
    int lane = tid & 63, w = tid >> 6;
    int g = lane >> 4, c = lane & 15;
    int bid = blockIdx.x;
    int b = bid & 3, qz = (bid >> 2) & 3;
    int j = bid >> 4, k4 = j >> 4, r4 = j & 15;
    // per-CU resident quadruple {r, 63-r, 16+r, 47-r} sums to constant work
    int qt = (k4 == 0) ? r4 : (k4 == 1) ? 63 - r4 : (k4 == 2) ? 16 + r4 : 47 - r4;
    int q0 = qt * 32;
    int qrow = q0 + w * 16;
    const u16* qp = q_ws + (size_t)(b * SEQ) * HS;
    const u16* kp = k_ws + (size_t)(b * SEQ) * HS;
    const u16* vp = vt_ws + (size_t)b * HS * SEQ;

    s16x8 qf[4];
#pragma unroll
    for (int kk = 0; kk < 4; ++kk)
        qf[kk] = *(const s16x8*)(qp + (size_t)(qrow + c) * HS + kk * 32 + 8 * g);

    f32x4 o[8] = {};
    float m[4], l[4];
#pragma unroll
    for (int r = 0; r < 4; ++r) { m[r] = -1e30f; l[r] = 0.f; }

    int nt = (q0 + 32 + 63) >> 6;
    for (int t = qz; t < nt; t += 4) {
        int kv0 = t * 64;
#pragma unroll
        for (int i = 0; i < 8; ++i) {
            int chunk = i * 128 + tid;
            int row = chunk >> 4, cc = chunk & 15;   // K: 64 rows x 16 chunks
            s16x8 va = *(const s16x8*)(kp + (size_t)(kv0 + row) * HS + cc * 8);
            *(s16x8*)(ks + row * 128 + ((cc ^ (row & 7)) * 8)) = va;
            int d = chunk >> 3, c2 = chunk & 7;      // V^T: 128 rows x 8 chunks
            s16x8 vb = *(const s16x8*)(vp + (size_t)d * SEQ + kv0 + c2 * 8);
            *(s16x8*)(vs + d * 64 + ((c2 ^ (d & 7)) * 8)) = vb;
        }
        __syncthreads();

        f32x4 s[4];
#pragma unroll
        for (int sub = 0; sub < 4; ++sub) {
            s[sub] = (f32x4){0.f, 0.f, 0.f, 0.f};
#pragma unroll
            for (int kk = 0; kk < 4; ++kk) {
                int row = sub * 16 + c;
                s16x8 kf = *(const s16x8*)(ks + row * 128 + (((kk * 4 + g) ^ (row & 7)) * 8));
                mfma16(s[sub], qf[kk], kf);
            }
        }
        float mt[4];
#pragma unroll
        for (int r = 0; r < 4; ++r) mt[r] = -1e30f;
#pragma unroll
        for (int sub = 0; sub < 4; ++sub) {
            int col = kv0 + sub * 16 + c;
#pragma unroll
            for (int r = 0; r < 4; ++r) {
                int rq = qrow + g * 4 + r;
                if (col > rq) s[sub][r] = -1e30f;
                mt[r] = fmaxf(mt[r], s[sub][r]);
            }
        }
#pragma unroll
        for (int r = 0; r < 4; ++r) {
            mt[r] = fmaxf(mt[r], __shfl_xor(mt[r], 1));
            mt[r] = fmaxf(mt[r], __shfl_xor(mt[r], 2));
            mt[r] = fmaxf(mt[r], __shfl_xor(mt[r], 4));
            mt[r] = fmaxf(mt[r], __shfl_xor(mt[r], 8));
        }
        float rs[4], sc[4];
#pragma unroll
        for (int r = 0; r < 4; ++r) {
            float mn = fmaxf(m[r], mt[r]);
            sc[r] = __expf(m[r] - mn);
            m[r] = mn;
            rs[r] = 0.f;
        }
#pragma unroll
        for (int sub = 0; sub < 4; ++sub)
#pragma unroll
            for (int r = 0; r < 4; ++r) {
                float p = __expf(s[sub][r] - m[r]);
                s[sub][r] = p;
                rs[r] += p;
            }
#pragma unroll
        for (int r = 0; r < 4; ++r) {
            rs[r] += __shfl_xor(rs[r], 1);
            rs[r] += __shfl_xor(rs[r], 2);
            rs[r] += __shfl_xor(rs[r], 4);
            rs[r] += __shfl_xor(rs[r], 8);
            l[r] = l[r] * sc[r] + rs[r];
        }
#pragma unroll
        for (int n = 0; n < 8; ++n)
#pragma unroll
            for (int r = 0; r < 4; ++r) o[n][r] *= sc[r];

#pragma unroll
        for (int sub = 0; sub < 4; ++sub)
#pragma unroll
            for (int r = 0; r < 4; ++r)
                ps[w * 1152 + (g * 4 + r) * 72 + sub * 16 + c] = f2bf(s[sub][r]);

#pragma unroll
        for (int kk = 0; kk < 2; ++kk) {
            s16x8 pf = *(const s16x8*)(ps + w * 1152 + c * 72 + kk * 32 + 8 * g);
#pragma unroll
            for (int n = 0; n < 8; ++n) {
                int d = n * 16 + c;
                s16x8 vf = *(const s16x8*)(vs + d * 64 + (((kk * 4 + g) ^ (d & 7)) * 8));
                mfma16(o[n], pf, vf);
            }
        }
        __syncthreads();
    }

    // write unnormalized partial (o, m, l)
    size_t pb = ((size_t)(b * 64 + qt) * 4 + qz) * 32;
#pragma unroll
    for (int r = 0; r < 4; ++r) {
        int row = w * 16 + g * 4 + r;
#pragma unroll
        for (int n = 0; n < 8; ++n)
            pa_o[(pb + row) * HS + n * 16 + c] = o[n][r];
        if (c == 0) {
            pa_m[pb + row] = m[r];
            pa_l[pb + row] = l[r];
        }
    }
}

// ---------------- combine 4 KV-split partials -> out fp32 ----------------
__global__ void attn_combine(const float* __restrict__ pa_o, const float* __restrict__ pa_m,
                             const float* __restrict__ pa_l, float* __restrict__ out) {
    int cid = blockIdx.x * 256 + threadIdx.x;   // 0..131071
    int row = cid >> 4, c8 = (cid & 15) * 8;    // row = global q row 0..8191
    int b = row >> 11, t = row & 2047;
    int qt = t >> 5, r32 = t & 31;
    size_t pbase = (size_t)(b * 64 + qt) * 128 + r32;   // = ((b*64+qt)*4 + 0)*32 + r32
    float mv[4], lv[4], mm = -1e30f;
#pragma unroll
    for (int w = 0; w < 4; ++w) {
        mv[w] = pa_m[pbase + w * 32];
        lv[w] = pa_l[pbase + w * 32];
        mm = fmaxf(mm, mv[w]);
    }
    float denom = 0.f, sw[4];
#pragma unroll
    for (int w = 0; w < 4; ++w) { sw[w] = __expf(mv[w] - mm); denom += lv[w] * sw[w]; }
    float inv = 1.0f / denom;
    float acc[8] = {0.f, 0.f, 0.f, 0.f, 0.f, 0.f, 0.f, 0.f};
#pragma unroll
    for (int w = 0; w < 4; ++w) {
        const float4* op = (const float4*)(pa_o + (pbase + w * 32) * HS + c8);
        float4 a = op[0], bb = op[1];
        acc[0] += a.x * sw[w]; acc[1] += a.y * sw[w];
        acc[2] += a.z * sw[w]; acc[3] += a.w * sw[w];
        acc[4] += bb.x * sw[w]; acc[5] += bb.y * sw[w];
        acc[6] += bb.z * sw[w]; acc[7] += bb.w * sw[w];
    }
    float4* od = (float4*)(out + (size_t)row * HS + c8);
    od[0] = (float4){acc[0] * inv, acc[1] * inv, acc[2] * inv, acc[3] * inv};
    od[1] = (float4){acc[4] * inv, acc[5] * inv, acc[6] * inv, acc[7] * inv};
}

extern "C" void kernel_launch(void* const* d_in, const int* in_sizes, int n_in,
                              void* d_out, int out_size, void* d_ws, size_t ws_size,
                              hipStream_t stream) {
    const float* x  = (const float*)d_in[0];
    const float* wq = (const float*)d_in[1];
    const float* bq = (const float*)d_in[2];
    const float* wk = (const float*)d_in[3];
    const float* bk = (const float*)d_in[4];
    const float* wv = (const float*)d_in[5];
    const float* bv = (const float*)d_in[6];
    float* out = (float*)d_out;

    char* ws = (char*)d_ws;
    u16* wt    = (u16*)ws;                                    // 3*128*2048*2   = 1.5 MB
    u16* part  = (u16*)(ws + 1572864);                        // 4*3*8192*128*2 = 25.2 MB
    u16* q_ws  = (u16*)(ws + 1572864 + 25165824);             // 2 MB
    u16* k_ws  = q_ws + (size_t)M_TOT * HS;                   // 2 MB
    u16* vt_ws = k_ws + (size_t)M_TOT * HS;                   // 2 MB
    // attention partials alias the (dead by then) proj partial buffer
    float* pa_o = (float*)(ws + 1572864);                     // 4*64*4*32*128*4 = 16.8 MB
    float* pa_m = pa_o + (size_t)4 * 64 * 4 * 32 * 128;       // 32768 floats
    float* pa_l = pa_m + 32768;

    hipLaunchKernelGGL(cvt_w, dim3(1024, 3), dim3(256), 0, stream, wq, wk, wv, wt);
    hipLaunchKernelGGL(proj_sk, dim3(64, 3, 4), dim3(256), 0, stream, x, wt, part);
    hipLaunchKernelGGL(reduce_qk, dim3(1024), dim3(256), 0, stream, part, bq, bk, q_ws, k_ws);
    hipLaunchKernelGGL(reduce_v, dim3(32, 4), dim3(256), 0, stream, part, bv, vt_ws);
    hipLaunchKernelGGL(attn_part, dim3(1024), dim3(128), 0, stream,
                       q_ws, k_ws, vt_ws, pa_o, pa_m, pa_l);
    hipLaunchKernelGGL(attn_combine, dim3(512), dim3(256), 0, stream,
                       pa_o, pa_m, pa_l, out);
}